// Round 6
// baseline (871.358 us; speedup 1.0000x reference)
//
#include <hip/hip_runtime.h>
#include <stdint.h>

// Pipeline (N=F=2048, E=131072):
//   deg/CSR build -> x->bf16 -> [GEMM -> gather(agg+self+bias+relu)] x2 (GCN)
//   -> 3x { 3-gate fused GEMM (bias fused) -> in-place pointwise LSTM act } -> final head
// All matmuls: bf16 MFMA 16x16x32, 128x128 tile, global_load_lds staging (m97 structure).
// ws usage: 7 x 8.4MB bf16 buffers + ~1.3MB CSR = ~59.8 MB (in-place LSTM act saves 1 buffer).

#define FDIM 2048
typedef unsigned short u16;
typedef unsigned int u32;

typedef __bf16 bf16x8 __attribute__((ext_vector_type(8)));
typedef float f32x4 __attribute__((ext_vector_type(4)));
typedef __attribute__((address_space(1))) void* as1p;
typedef __attribute__((address_space(3))) void* as3p;

__device__ __forceinline__ float bflo(u32 u) { return __uint_as_float(u << 16); }
__device__ __forceinline__ float bfhi(u32 u) { return __uint_as_float(u & 0xffff0000u); }
__device__ __forceinline__ u16 f2b(float f) {
    u32 u = __float_as_uint(f);
    return (u16)((u + 0x7fffu + ((u >> 16) & 1u)) >> 16);  // RNE
}
__device__ __forceinline__ void unp8(const uint4 v, float* f) {
    f[0] = bflo(v.x); f[1] = bfhi(v.x); f[2] = bflo(v.y); f[3] = bfhi(v.y);
    f[4] = bflo(v.z); f[5] = bfhi(v.z); f[6] = bflo(v.w); f[7] = bfhi(v.w);
}
__device__ __forceinline__ uint4 pk8(const float* f) {
    uint4 v;
    v.x = (u32)f2b(f[0]) | ((u32)f2b(f[1]) << 16);
    v.y = (u32)f2b(f[2]) | ((u32)f2b(f[3]) << 16);
    v.z = (u32)f2b(f[4]) | ((u32)f2b(f[5]) << 16);
    v.w = (u32)f2b(f[6]) | ((u32)f2b(f[7]) << 16);
    return v;
}

// ---------------- CSR build ----------------
__global__ void k_zero(int* __restrict__ p, int n) {
    int i = blockIdx.x * 256 + threadIdx.x;
    if (i < n) p[i] = 0;
}

__global__ void k_hist(const int* __restrict__ ei, int* __restrict__ counts, int ne) {
    int e = blockIdx.x * 256 + threadIdx.x;
    if (e < ne) atomicAdd(&counts[ei[ne + e]], 1);  // dst = ei[1][e]
}

// 1 block, 1024 threads: exclusive scan of counts[2048] -> off, plus dinv = rsqrt(deg+2)
__global__ __launch_bounds__(1024) void k_scan(const int* __restrict__ counts,
                                               int* __restrict__ off,
                                               float* __restrict__ dinv) {
    __shared__ int sb[2][FDIM];
    const int t = threadIdx.x;
    const int c0 = counts[t], c1 = counts[t + 1024];
    sb[0][t] = c0; sb[0][t + 1024] = c1;
    __syncthreads();
    int cur = 0;
    for (int st = 1; st < FDIM; st <<= 1) {
        const int i1 = t + 1024;
        int v0 = sb[cur][t] + (t >= st ? sb[cur][t - st] : 0);
        int v1 = sb[cur][i1] + (i1 >= st ? sb[cur][i1 - st] : 0);
        sb[cur ^ 1][t] = v0; sb[cur ^ 1][i1] = v1;
        __syncthreads();
        cur ^= 1;
    }
    off[t] = sb[cur][t] - c0;
    off[t + 1024] = sb[cur][t + 1024] - c1;
    if (t == 0) off[FDIM] = sb[cur][FDIM - 1];
    dinv[t] = rsqrtf((float)c0 + 2.0f);
    dinv[t + 1024] = rsqrtf((float)c1 + 2.0f);
}

__global__ void k_fill(const int* __restrict__ ei, const int* __restrict__ off,
                       int* __restrict__ cursor, const float* __restrict__ dinv,
                       int* __restrict__ csr_s, float* __restrict__ csr_w, int ne) {
    int e = blockIdx.x * 256 + threadIdx.x;
    if (e >= ne) return;
    int s = ei[e], d = ei[ne + e];
    int p = atomicAdd(&cursor[d], 1);
    int idx = off[d] + p;
    csr_s[idx] = s;
    csr_w[idx] = dinv[s] * dinv[d];
}

// ---------------- conversions ----------------
// fp32 -> bf16, 8 elems/thread. grid*block*8 == FDIM*FDIM exactly.
__global__ void k_f2b8(const float* __restrict__ x, u16* __restrict__ o) {
    const int i = blockIdx.x * 256 + threadIdx.x;
    const size_t base = (size_t)i * 8;
    float f[8];
    *(float4*)(f)     = *(const float4*)(x + base);
    *(float4*)(f + 4) = *(const float4*)(x + base + 4);
    *(uint4*)(o + base) = pk8(f);
}

// W[k][n] fp32 -> Wt[n][k] bf16, 32x32 LDS tiles
__global__ __launch_bounds__(1024) void k_transp(const float* __restrict__ W,
                                                 u16* __restrict__ Wt) {
    __shared__ float tile[32][33];
    const int tx = threadIdx.x & 31, ty = threadIdx.x >> 5;
    const int bx = blockIdx.x * 32, by = blockIdx.y * 32;
    tile[ty][tx] = W[(size_t)(by + ty) * FDIM + bx + tx];
    __syncthreads();
    Wt[(size_t)(bx + ty) * FDIM + by + tx] = f2b(tile[tx][ty]);
}

// ---------------- GEMM ----------------
// C[2048][2048] = A @ B where A bf16 [M][K] row-major, Bt bf16 [N][K] (B transposed).
// 128x128 tile, BK=32, 4 waves, each wave a 64x64 subtile (4x4 16x16 fragments).
struct GemmArgs {
    const u16* A;
    const u16* Bt[3];
    u16* C[3];
    const float* b1[3];
    const float* b2[3];
};

__global__ __launch_bounds__(256) void k_gemm(GemmArgs ga) {
    const int z = blockIdx.z;
    const u16* __restrict__ A  = ga.A;
    const u16* __restrict__ Bt = ga.Bt[z];

    const int tid = threadIdx.x;
    const int wid = tid >> 6;
    const int lane = tid & 63;
    const int wr = wid >> 1, wc = wid & 1;
    const int lr = lane & 15, lg = lane >> 4;
    const int brow = blockIdx.y * 128;
    const int bcol = blockIdx.x * 128;

    __shared__ u16 As[128 * 32];
    __shared__ u16 Bs[128 * 32];

    f32x4 acc[4][4];
#pragma unroll
    for (int m = 0; m < 4; ++m)
#pragma unroll
        for (int n = 0; n < 4; ++n) acc[m][n] = (f32x4){0.f, 0.f, 0.f, 0.f};

    // staging geometry: wave w, issue q covers LDS bytes [(q*4+w)*1024, +1024)
    const u16* gA[2]; const u16* gB[2];
    u16* lA[2]; u16* lB[2];
#pragma unroll
    for (int q = 0; q < 2; ++q) {
        const int seg = q * 4 + wid;              // 0..7 (wave-uniform)
        const int row = seg * 16 + (lane >> 2);   // 0..127
        const int ke  = (lane & 3) * 8;           // k element offset 0/8/16/24
        gA[q] = A  + (size_t)(brow + row) * FDIM + ke;
        gB[q] = Bt + (size_t)(bcol + row) * FDIM + ke;
        lA[q] = As + seg * 512;                   // wave-uniform LDS base
        lB[q] = Bs + seg * 512;
    }

    int aoff[4], boff[4];
#pragma unroll
    for (int m = 0; m < 4; ++m) aoff[m] = (wr * 64 + m * 16 + lr) * 32 + lg * 8;
#pragma unroll
    for (int n = 0; n < 4; ++n) boff[n] = (wc * 64 + n * 16 + lr) * 32 + lg * 8;

    for (int kt = 0; kt < FDIM / 32; ++kt) {
        const int ko = kt * 32;
        __builtin_amdgcn_global_load_lds((as1p)(u16*)(gA[0] + ko), (as3p)lA[0], 16, 0, 0);
        __builtin_amdgcn_global_load_lds((as1p)(u16*)(gA[1] + ko), (as3p)lA[1], 16, 0, 0);
        __builtin_amdgcn_global_load_lds((as1p)(u16*)(gB[0] + ko), (as3p)lB[0], 16, 0, 0);
        __builtin_amdgcn_global_load_lds((as1p)(u16*)(gB[1] + ko), (as3p)lB[1], 16, 0, 0);
        __syncthreads();  // drains vmcnt before barrier (compiler-inserted)

        bf16x8 av[4], bv[4];
#pragma unroll
        for (int m = 0; m < 4; ++m) av[m] = *reinterpret_cast<const bf16x8*>(&As[aoff[m]]);
#pragma unroll
        for (int n = 0; n < 4; ++n) bv[n] = *reinterpret_cast<const bf16x8*>(&Bs[boff[n]]);
#pragma unroll
        for (int m = 0; m < 4; ++m)
#pragma unroll
            for (int n = 0; n < 4; ++n)
                acc[m][n] = __builtin_amdgcn_mfma_f32_16x16x32_bf16(av[m], bv[n], acc[m][n], 0, 0, 0);
        __syncthreads();
    }

    u16* __restrict__ C = ga.C[z];
    const float* b1 = ga.b1[z];
    const float* b2 = ga.b2[z];
#pragma unroll
    for (int n = 0; n < 4; ++n) {
        const int col = bcol + wc * 64 + n * 16 + lr;
        float badd = 0.f;
        if (b1) badd = b1[col] + b2[col];
#pragma unroll
        for (int m = 0; m < 4; ++m) {
            const int row0 = brow + wr * 64 + m * 16 + lg * 4;
#pragma unroll
            for (int r = 0; r < 4; ++r)
                C[(size_t)(row0 + r) * FDIM + col] = f2b(acc[m][n][r] + badd);
        }
    }
}

// ---------------- GCN edge aggregation ----------------
// block = dst node n; thread t owns features [8t, 8t+8).
// out[n][f] = relu( sum_e w_e * h[src_e][f] + 2*dinv[n]^2 * h[n][f] + bias[f] ), bf16 out.
__global__ __launch_bounds__(256) void k_gather(
    const u16* __restrict__ Hp, const int* __restrict__ off,
    const int* __restrict__ csr_s, const float* __restrict__ csr_w,
    const float* __restrict__ dinv, const float* __restrict__ bias,
    u16* __restrict__ outb) {
    const int n = blockIdx.x, t = threadIdx.x;
    __shared__ int s_src[256];
    __shared__ float s_w[256];
    float acc[8] = {0.f, 0.f, 0.f, 0.f, 0.f, 0.f, 0.f, 0.f};
    const int e0 = off[n], e1 = off[n + 1];
    const int fb = t * 8;
    for (int base = e0; base < e1; base += 256) {
        const int cnt = min(256, e1 - base);
        __syncthreads();
        if (t < cnt) { s_src[t] = csr_s[base + t]; s_w[t] = csr_w[base + t]; }
        __syncthreads();
        for (int i = 0; i < cnt; ++i) {
            const int s = s_src[i];
            const float w = s_w[i];
            const uint4 v = *reinterpret_cast<const uint4*>(Hp + (size_t)s * FDIM + fb);
            float f[8]; unp8(v, f);
#pragma unroll
            for (int j = 0; j < 8; ++j) acc[j] = fmaf(w, f[j], acc[j]);
        }
    }
    const float di = dinv[n];
    const float sw = 2.f * di * di;
    {
        const uint4 v = *reinterpret_cast<const uint4*>(Hp + (size_t)n * FDIM + fb);
        float f[8]; unp8(v, f);
#pragma unroll
        for (int j = 0; j < 8; ++j) acc[j] = fmaf(sw, f[j], acc[j]);
    }
    float bb[8];
    *(float4*)(bb)     = *(const float4*)(bias + fb);
    *(float4*)(bb + 4) = *(const float4*)(bias + fb + 4);
    float r[8];
#pragma unroll
    for (int j = 0; j < 8; ++j) r[j] = fmaxf(acc[j] + bb[j], 0.f);
    *reinterpret_cast<uint4*>(outb + (size_t)n * FDIM + fb) = pk8(r);
}

// ---------------- LSTM pointwise (H=C=0 simplification) ----------------
// Cn = sigmoid(gi)*tanh(gc); Hn = sigmoid(go + wc2[f]*Cn)*tanh(Cn)
// NOTE: Ho may alias gi (in-place). Read-then-write is strictly thread-local and
// index-aligned, so no cross-thread hazard; gi/Ho intentionally NOT __restrict__.
__global__ void k_lstm_act(const u16* gi, const u16* __restrict__ gc,
                           const u16* __restrict__ go, const float* __restrict__ wc2,
                           u16* Ho) {
    const int i = blockIdx.x * 256 + threadIdx.x;
    const size_t base = (size_t)i * 8;
    const int f = (int)(base & (FDIM - 1));
    const uint4 vi = *(const uint4*)(gi + base);
    const uint4 vc = *(const uint4*)(gc + base);
    const uint4 vo = *(const uint4*)(go + base);
    float fi[8], fc[8], fo[8], w[8], h[8];
    unp8(vi, fi); unp8(vc, fc); unp8(vo, fo);
    *(float4*)(w)     = *(const float4*)(wc2 + f);
    *(float4*)(w + 4) = *(const float4*)(wc2 + f + 4);
#pragma unroll
    for (int j = 0; j < 8; ++j) {
        const float I  = 1.f / (1.f + __expf(-fi[j]));
        const float Cn = I * tanhf(fc[j]);
        const float O  = 1.f / (1.f + __expf(-(fo[j] + w[j] * Cn)));
        h[j] = O * tanhf(Cn);
    }
    *(uint4*)(Ho + base) = pk8(h);
}

// ---------------- final: relu -> [2048,9] linear -> log_softmax over triples ----------------
__global__ __launch_bounds__(256) void k_final(const u16* __restrict__ Hf,
                                               const float* __restrict__ lw,
                                               const float* __restrict__ lb,
                                               float* __restrict__ out) {
    const int n = blockIdx.x, t = threadIdx.x;
    float p[9] = {0.f, 0.f, 0.f, 0.f, 0.f, 0.f, 0.f, 0.f, 0.f};
    for (int f = t; f < FDIM; f += 256) {
        float h = __uint_as_float(((u32)Hf[(size_t)n * FDIM + f]) << 16);
        h = fmaxf(h, 0.f);
#pragma unroll
        for (int j = 0; j < 9; ++j) p[j] = fmaf(h, lw[j * FDIM + f], p[j]);
    }
    __shared__ float red[9][256];
#pragma unroll
    for (int j = 0; j < 9; ++j) red[j][t] = p[j];
    __syncthreads();
    for (int s = 128; s > 0; s >>= 1) {
        if (t < s) {
#pragma unroll
            for (int j = 0; j < 9; ++j) red[j][t] += red[j][t + s];
        }
        __syncthreads();
    }
    if (t == 0) {
        float y[9];
#pragma unroll
        for (int j = 0; j < 9; ++j) y[j] = red[j][0] + lb[j];
#pragma unroll
        for (int g = 0; g < 3; ++g) {
            const float a = y[g * 3], b = y[g * 3 + 1], c = y[g * 3 + 2];
            const float m = fmaxf(a, fmaxf(b, c));
            const float lse = m + logf(__expf(a - m) + __expf(b - m) + __expf(c - m));
            out[n * 9 + g * 3 + 0] = a - lse;
            out[n * 9 + g * 3 + 1] = b - lse;
            out[n * 9 + g * 3 + 2] = c - lse;
        }
    }
}

// ---------------- launcher ----------------
extern "C" void kernel_launch(void* const* d_in, const int* in_sizes, int n_in,
                              void* d_out, int out_size, void* d_ws, size_t ws_size,
                              hipStream_t stream) {
    const float* x   = (const float*)d_in[0];
    const int*   ei  = (const int*)d_in[1];
    const float* g1w = (const float*)d_in[3];
    const float* g1b = (const float*)d_in[4];
    const float* g2w = (const float*)d_in[5];
    const float* g2b = (const float*)d_in[6];
    const float* Wx  = (const float*)d_in[7];
    // d_in[8] = lstm_Th: dead (H=0)
    const float* bch = (const float*)d_in[9];
    const float* wcv = (const float*)d_in[10];
    const float* bb  = (const float*)d_in[11];
    const float* lw  = (const float*)d_in[12];
    const float* lb  = (const float*)d_in[13];
    float* out = (float*)d_out;

    const int NE = in_sizes[1] / 2;  // 131072
    const size_t FF = (size_t)FDIM * FDIM;

    // --- workspace layout (with overflow tripwire) ---
    const size_t BUF = (FF * 2 + 255) & ~(size_t)255;  // 8.39 MB
    const size_t csr_bytes = ((size_t)FDIM * 8 + ((size_t)FDIM + 1) * 4 + (size_t)FDIM * 4
                              + (size_t)NE * 8 + 4 * 256);
    const size_t needed = 7 * BUF + csr_bytes;

    char* wp = (char*)d_ws;
    bool fallback = (ws_size < needed);  // aliased layout: garbage output, but no OOB fault
    auto alloc = [&](size_t bytes) -> void* {
        if (fallback) return d_ws;  // everything at base (<= 16.8MB per-kernel extent)
        void* p = (void*)wp;
        wp += (bytes + 255) & ~(size_t)255;
        return p;
    };
    u16* A0 = (u16*)alloc(FF * 2);
    u16* A1 = (u16*)alloc(FF * 2);
    u16* G1 = (u16*)alloc(FF * 2);
    u16* G2 = (u16*)alloc(FF * 2);
    u16* WT0 = (u16*)alloc(FF * 2);
    u16* WT1 = (u16*)alloc(FF * 2);
    u16* WT2 = (u16*)alloc(FF * 2);
    int*   counts;
    int*   off;
    float* dinv;
    int*   csr_s;
    float* csr_w;
    if (!fallback) {
        counts = (int*)alloc((size_t)FDIM * 4 * 2);  // counts + cursor
        off    = (int*)alloc(((size_t)FDIM + 1) * 4);
        dinv   = (float*)alloc((size_t)FDIM * 4);
        csr_s  = (int*)alloc((size_t)NE * 4);
        csr_w  = (float*)alloc((size_t)NE * 4);
    } else {
        char* base = (char*)d_ws;
        counts = (int*)base;
        off    = (int*)(base + (size_t)64 * 1024);
        dinv   = (float*)(base + (size_t)128 * 1024);
        csr_s  = (int*)(base + (size_t)1024 * 1024);
        csr_w  = (float*)(base + (size_t)2048 * 1024);
    }
    int* cursor = counts + FDIM;

    const int eb = (NE + 255) / 256;
    const dim3 tg(64, 64), tb(1024);
    const dim3 gb(256);

    // CSR build
    k_zero<<<dim3((2 * FDIM + 255) / 256), dim3(256), 0, stream>>>(counts, 2 * FDIM);
    k_hist<<<dim3(eb), dim3(256), 0, stream>>>(ei, counts, NE);
    k_scan<<<dim3(1), dim3(1024), 0, stream>>>(counts, off, dinv);
    k_fill<<<dim3(eb), dim3(256), 0, stream>>>(ei, off, cursor, dinv, csr_s, csr_w, NE);

    // x -> bf16
    k_f2b8<<<dim3(2048), dim3(256), 0, stream>>>(x, A0);

    GemmArgs ga;
    // GCN layer 1: h_pre = A0 @ W1 -> A1 ; gather(A1) -> G1
    k_transp<<<tg, tb, 0, stream>>>(g1w, WT0);
    ga.A = A0;
    for (int s = 0; s < 3; ++s) { ga.Bt[s] = WT0; ga.C[s] = A1; ga.b1[s] = nullptr; ga.b2[s] = nullptr; }
    k_gemm<<<dim3(16, 16, 1), gb, 0, stream>>>(ga);
    k_gather<<<dim3(FDIM), dim3(256), 0, stream>>>(A1, off, csr_s, csr_w, dinv, g1b, G1);
    // GCN layer 2: h_pre = G1 @ W2 -> A1 ; gather(A1) -> A0
    k_transp<<<tg, tb, 0, stream>>>(g2w, WT0);
    ga.A = G1;
    k_gemm<<<dim3(16, 16, 1), gb, 0, stream>>>(ga);
    k_gather<<<dim3(FDIM), dim3(256), 0, stream>>>(A1, off, csr_s, csr_w, dinv, g2b, A0);

    // 3 GCLSTM layers (gates i=0, c=2, o=3; f-gate and Th dead since H=C=0).
    // Gate-i buffer doubles as H output (in-place act) -> A0/A1 ping-pong.
    u16* cur = A0;
    u16* alt = A1;
    for (int l = 0; l < 3; ++l) {
        const int gsel[3] = {0, 2, 3};
        u16* wts[3]   = {WT0, WT1, WT2};
        u16* gouts[3] = {alt, G1, G2};  // gi -> alt (becomes next cur), gc -> G1, go -> G2
        for (int s = 0; s < 3; ++s)
            k_transp<<<tg, tb, 0, stream>>>(Wx + (size_t)(l * 4 + gsel[s]) * FF, wts[s]);
        GemmArgs gl;
        gl.A = cur;
        for (int s = 0; s < 3; ++s) {
            gl.Bt[s] = wts[s];
            gl.C[s]  = gouts[s];
            gl.b1[s] = bch + (size_t)(l * 4 + gsel[s]) * FDIM;
            gl.b2[s] = bb  + (size_t)(l * 4 + gsel[s]) * FDIM;
        }
        k_gemm<<<dim3(16, 16, 3), gb, 0, stream>>>(gl);
        k_lstm_act<<<dim3(2048), dim3(256), 0, stream>>>(alt, G1, G2,
                                                         wcv + (size_t)(l * 3 + 2) * FDIM, alt);
        u16* tmp = cur; cur = alt; alt = tmp;  // H now in old `alt`
    }

    // final head (cur holds H of last LSTM layer)
    k_final<<<dim3(FDIM), dim3(256), 0, stream>>>(cur, lw, lb, out);
}

// Round 7
// 870.109 us; speedup vs baseline: 1.0014x; 1.0014x over previous
//
#include <hip/hip_runtime.h>
#include <stdint.h>

// Pipeline (N=F=2048, E=131072):
//   one batched weight-transpose (z=11) -> CSR build -> x->bf16
//   -> [split-K GEMM -> combine -> gather(agg+self+bias+relu)] x2 (GCN)
//   -> 3x { 3-gate fused GEMM z=3 (bias fused) -> in-place pointwise LSTM act } -> final head
// Matmuls: bf16 MFMA 16x16x32, 128x128 tile, global_load_lds staging (m97 structure).
// ws usage: 4 act + 11 WT bf16 buffers + 32MB fp32 partials + ~1.3MB CSR = ~161 MB (ws=768MiB).

#define FDIM 2048
typedef unsigned short u16;
typedef unsigned int u32;

typedef __bf16 bf16x8 __attribute__((ext_vector_type(8)));
typedef float f32x4 __attribute__((ext_vector_type(4)));
typedef __attribute__((address_space(1))) void* as1p;
typedef __attribute__((address_space(3))) void* as3p;

__device__ __forceinline__ float bflo(u32 u) { return __uint_as_float(u << 16); }
__device__ __forceinline__ float bfhi(u32 u) { return __uint_as_float(u & 0xffff0000u); }
__device__ __forceinline__ u16 f2b(float f) {
    u32 u = __float_as_uint(f);
    return (u16)((u + 0x7fffu + ((u >> 16) & 1u)) >> 16);  // RNE
}
__device__ __forceinline__ void unp8(const uint4 v, float* f) {
    f[0] = bflo(v.x); f[1] = bfhi(v.x); f[2] = bflo(v.y); f[3] = bfhi(v.y);
    f[4] = bflo(v.z); f[5] = bfhi(v.z); f[6] = bflo(v.w); f[7] = bfhi(v.w);
}
__device__ __forceinline__ uint4 pk8(const float* f) {
    uint4 v;
    v.x = (u32)f2b(f[0]) | ((u32)f2b(f[1]) << 16);
    v.y = (u32)f2b(f[2]) | ((u32)f2b(f[3]) << 16);
    v.z = (u32)f2b(f[4]) | ((u32)f2b(f[5]) << 16);
    v.w = (u32)f2b(f[6]) | ((u32)f2b(f[7]) << 16);
    return v;
}

// ---------------- CSR build ----------------
__global__ void k_zero(int* __restrict__ p, int n) {
    int i = blockIdx.x * 256 + threadIdx.x;
    if (i < n) p[i] = 0;
}

__global__ void k_hist(const int* __restrict__ ei, int* __restrict__ counts, int ne) {
    int e = blockIdx.x * 256 + threadIdx.x;
    if (e < ne) atomicAdd(&counts[ei[ne + e]], 1);  // dst = ei[1][e]
}

// 1 block, 1024 threads: exclusive scan of counts[2048] -> off, plus dinv = rsqrt(deg+2)
__global__ __launch_bounds__(1024) void k_scan(const int* __restrict__ counts,
                                               int* __restrict__ off,
                                               float* __restrict__ dinv) {
    __shared__ int sb[2][FDIM];
    const int t = threadIdx.x;
    const int c0 = counts[t], c1 = counts[t + 1024];
    sb[0][t] = c0; sb[0][t + 1024] = c1;
    __syncthreads();
    int cur = 0;
    for (int st = 1; st < FDIM; st <<= 1) {
        const int i1 = t + 1024;
        int v0 = sb[cur][t] + (t >= st ? sb[cur][t - st] : 0);
        int v1 = sb[cur][i1] + (i1 >= st ? sb[cur][i1 - st] : 0);
        sb[cur ^ 1][t] = v0; sb[cur ^ 1][i1] = v1;
        __syncthreads();
        cur ^= 1;
    }
    off[t] = sb[cur][t] - c0;
    off[t + 1024] = sb[cur][t + 1024] - c1;
    if (t == 0) off[FDIM] = sb[cur][FDIM - 1];
    dinv[t] = rsqrtf((float)c0 + 2.0f);
    dinv[t + 1024] = rsqrtf((float)c1 + 2.0f);
}

__global__ void k_fill(const int* __restrict__ ei, const int* __restrict__ off,
                       int* __restrict__ cursor, const float* __restrict__ dinv,
                       int* __restrict__ csr_s, float* __restrict__ csr_w, int ne) {
    int e = blockIdx.x * 256 + threadIdx.x;
    if (e >= ne) return;
    int s = ei[e], d = ei[ne + e];
    int p = atomicAdd(&cursor[d], 1);
    int idx = off[d] + p;
    csr_s[idx] = s;
    csr_w[idx] = dinv[s] * dinv[d];
}

// ---------------- conversions ----------------
// fp32 -> bf16, 8 elems/thread. grid*block*8 == FDIM*FDIM exactly.
__global__ void k_f2b8(const float* __restrict__ x, u16* __restrict__ o) {
    const int i = blockIdx.x * 256 + threadIdx.x;
    const size_t base = (size_t)i * 8;
    float f[8];
    *(float4*)(f)     = *(const float4*)(x + base);
    *(float4*)(f + 4) = *(const float4*)(x + base + 4);
    *(uint4*)(o + base) = pk8(f);
}

// Batched: 11 weight matrices W[k][n] fp32 -> WT[z][n][k] bf16, 32x32 LDS tiles.
struct TranspArgs { const float* W[11]; u16* WT; };
__global__ __launch_bounds__(1024) void k_transp_all(TranspArgs ta) {
    const float* __restrict__ W = ta.W[blockIdx.z];
    u16* __restrict__ Wt = ta.WT + (size_t)blockIdx.z * FDIM * FDIM;
    __shared__ float tile[32][33];
    const int tx = threadIdx.x & 31, ty = threadIdx.x >> 5;
    const int bx = blockIdx.x * 32, by = blockIdx.y * 32;
    tile[ty][tx] = W[(size_t)(by + ty) * FDIM + bx + tx];
    __syncthreads();
    Wt[(size_t)(bx + ty) * FDIM + by + tx] = f2b(tile[tx][ty]);
}

// ---------------- GEMM (z-batched over 3 weight sets; bias fused; bf16 out) ----------------
// C = A @ B, A bf16 [M][K] row-major, Bt bf16 [N][K]. 128x128 tile, BK=32, 4 waves.
struct GemmArgs {
    const u16* A;
    const u16* Bt[3];
    u16* C[3];
    const float* b1[3];
    const float* b2[3];
};

__global__ __launch_bounds__(256) void k_gemm(GemmArgs ga) {
    const int z = blockIdx.z;
    const u16* __restrict__ A  = ga.A;
    const u16* __restrict__ Bt = ga.Bt[z];

    const int tid = threadIdx.x;
    const int wid = tid >> 6;
    const int lane = tid & 63;
    const int wr = wid >> 1, wc = wid & 1;
    const int lr = lane & 15, lg = lane >> 4;
    const int brow = blockIdx.y * 128;
    const int bcol = blockIdx.x * 128;

    __shared__ u16 As[128 * 32];
    __shared__ u16 Bs[128 * 32];

    f32x4 acc[4][4];
#pragma unroll
    for (int m = 0; m < 4; ++m)
#pragma unroll
        for (int n = 0; n < 4; ++n) acc[m][n] = (f32x4){0.f, 0.f, 0.f, 0.f};

    const u16* gA[2]; const u16* gB[2];
    u16* lA[2]; u16* lB[2];
#pragma unroll
    for (int q = 0; q < 2; ++q) {
        const int seg = q * 4 + wid;              // 0..7 (wave-uniform)
        const int row = seg * 16 + (lane >> 2);   // 0..127
        const int ke  = (lane & 3) * 8;           // k element offset 0/8/16/24
        gA[q] = A  + (size_t)(brow + row) * FDIM + ke;
        gB[q] = Bt + (size_t)(bcol + row) * FDIM + ke;
        lA[q] = As + seg * 512;                   // wave-uniform LDS base
        lB[q] = Bs + seg * 512;
    }

    int aoff[4], boff[4];
#pragma unroll
    for (int m = 0; m < 4; ++m) aoff[m] = (wr * 64 + m * 16 + lr) * 32 + lg * 8;
#pragma unroll
    for (int n = 0; n < 4; ++n) boff[n] = (wc * 64 + n * 16 + lr) * 32 + lg * 8;

    for (int kt = 0; kt < FDIM / 32; ++kt) {
        const int ko = kt * 32;
        __builtin_amdgcn_global_load_lds((as1p)(u16*)(gA[0] + ko), (as3p)lA[0], 16, 0, 0);
        __builtin_amdgcn_global_load_lds((as1p)(u16*)(gA[1] + ko), (as3p)lA[1], 16, 0, 0);
        __builtin_amdgcn_global_load_lds((as1p)(u16*)(gB[0] + ko), (as3p)lB[0], 16, 0, 0);
        __builtin_amdgcn_global_load_lds((as1p)(u16*)(gB[1] + ko), (as3p)lB[1], 16, 0, 0);
        __syncthreads();

        bf16x8 av[4], bv[4];
#pragma unroll
        for (int m = 0; m < 4; ++m) av[m] = *reinterpret_cast<const bf16x8*>(&As[aoff[m]]);
#pragma unroll
        for (int n = 0; n < 4; ++n) bv[n] = *reinterpret_cast<const bf16x8*>(&Bs[boff[n]]);
#pragma unroll
        for (int m = 0; m < 4; ++m)
#pragma unroll
            for (int n = 0; n < 4; ++n)
                acc[m][n] = __builtin_amdgcn_mfma_f32_16x16x32_bf16(av[m], bv[n], acc[m][n], 0, 0, 0);
        __syncthreads();
    }

    u16* __restrict__ C = ga.C[z];
    const float* b1 = ga.b1[z];
    const float* b2 = ga.b2[z];
#pragma unroll
    for (int n = 0; n < 4; ++n) {
        const int col = bcol + wc * 64 + n * 16 + lr;
        float badd = 0.f;
        if (b1) badd = b1[col] + b2[col];
#pragma unroll
        for (int m = 0; m < 4; ++m) {
            const int row0 = brow + wr * 64 + m * 16 + lg * 4;
#pragma unroll
            for (int r = 0; r < 4; ++r)
                C[(size_t)(row0 + r) * FDIM + col] = f2b(acc[m][n][r] + badd);
        }
    }
}

// ---------------- split-K GEMM (K halves -> fp32 partials; 2 blocks/CU) ----------------
__global__ __launch_bounds__(256) void k_gemm_sk(const u16* __restrict__ A,
                                                const u16* __restrict__ Bt,
                                                float* __restrict__ P) {
    const int kz = blockIdx.z;  // K-half 0/1
    const int tid = threadIdx.x;
    const int wid = tid >> 6;
    const int lane = tid & 63;
    const int wr = wid >> 1, wc = wid & 1;
    const int lr = lane & 15, lg = lane >> 4;
    const int brow = blockIdx.y * 128;
    const int bcol = blockIdx.x * 128;

    __shared__ u16 As[128 * 32];
    __shared__ u16 Bs[128 * 32];

    f32x4 acc[4][4];
#pragma unroll
    for (int m = 0; m < 4; ++m)
#pragma unroll
        for (int n = 0; n < 4; ++n) acc[m][n] = (f32x4){0.f, 0.f, 0.f, 0.f};

    const u16* gA[2]; const u16* gB[2];
    u16* lA[2]; u16* lB[2];
#pragma unroll
    for (int q = 0; q < 2; ++q) {
        const int seg = q * 4 + wid;
        const int row = seg * 16 + (lane >> 2);
        const int ke  = (lane & 3) * 8;
        gA[q] = A  + (size_t)(brow + row) * FDIM + kz * 1024 + ke;
        gB[q] = Bt + (size_t)(bcol + row) * FDIM + kz * 1024 + ke;
        lA[q] = As + seg * 512;
        lB[q] = Bs + seg * 512;
    }

    int aoff[4], boff[4];
#pragma unroll
    for (int m = 0; m < 4; ++m) aoff[m] = (wr * 64 + m * 16 + lr) * 32 + lg * 8;
#pragma unroll
    for (int n = 0; n < 4; ++n) boff[n] = (wc * 64 + n * 16 + lr) * 32 + lg * 8;

    for (int kt = 0; kt < 1024 / 32; ++kt) {
        const int ko = kt * 32;
        __builtin_amdgcn_global_load_lds((as1p)(u16*)(gA[0] + ko), (as3p)lA[0], 16, 0, 0);
        __builtin_amdgcn_global_load_lds((as1p)(u16*)(gA[1] + ko), (as3p)lA[1], 16, 0, 0);
        __builtin_amdgcn_global_load_lds((as1p)(u16*)(gB[0] + ko), (as3p)lB[0], 16, 0, 0);
        __builtin_amdgcn_global_load_lds((as1p)(u16*)(gB[1] + ko), (as3p)lB[1], 16, 0, 0);
        __syncthreads();

        bf16x8 av[4], bv[4];
#pragma unroll
        for (int m = 0; m < 4; ++m) av[m] = *reinterpret_cast<const bf16x8*>(&As[aoff[m]]);
#pragma unroll
        for (int n = 0; n < 4; ++n) bv[n] = *reinterpret_cast<const bf16x8*>(&Bs[boff[n]]);
#pragma unroll
        for (int m = 0; m < 4; ++m)
#pragma unroll
            for (int n = 0; n < 4; ++n)
                acc[m][n] = __builtin_amdgcn_mfma_f32_16x16x32_bf16(av[m], bv[n], acc[m][n], 0, 0, 0);
        __syncthreads();
    }

    float* __restrict__ Pz = P + (size_t)kz * FDIM * FDIM;
#pragma unroll
    for (int n = 0; n < 4; ++n) {
        const int col = bcol + wc * 64 + n * 16 + lr;
#pragma unroll
        for (int m = 0; m < 4; ++m) {
            const int row0 = brow + wr * 64 + m * 16 + lg * 4;
#pragma unroll
            for (int r = 0; r < 4; ++r)
                Pz[(size_t)(row0 + r) * FDIM + col] = acc[m][n][r];
        }
    }
}

// combine split-K partials -> bf16
__global__ void k_comb(const float* __restrict__ P, u16* __restrict__ o) {
    const int i = blockIdx.x * 256 + threadIdx.x;
    const size_t base = (size_t)i * 8;
    const size_t FF = (size_t)FDIM * FDIM;
    float a[8], b[8], f[8];
    *(float4*)(a)     = *(const float4*)(P + base);
    *(float4*)(a + 4) = *(const float4*)(P + base + 4);
    *(float4*)(b)     = *(const float4*)(P + FF + base);
    *(float4*)(b + 4) = *(const float4*)(P + FF + base + 4);
#pragma unroll
    for (int j = 0; j < 8; ++j) f[j] = a[j] + b[j];
    *(uint4*)(o + base) = pk8(f);
}

// ---------------- GCN edge aggregation ----------------
__global__ __launch_bounds__(256) void k_gather(
    const u16* __restrict__ Hp, const int* __restrict__ off,
    const int* __restrict__ csr_s, const float* __restrict__ csr_w,
    const float* __restrict__ dinv, const float* __restrict__ bias,
    u16* __restrict__ outb) {
    const int n = blockIdx.x, t = threadIdx.x;
    __shared__ int s_src[256];
    __shared__ float s_w[256];
    float acc[8] = {0.f, 0.f, 0.f, 0.f, 0.f, 0.f, 0.f, 0.f};
    const int e0 = off[n], e1 = off[n + 1];
    const int fb = t * 8;
    for (int base = e0; base < e1; base += 256) {
        const int cnt = min(256, e1 - base);
        __syncthreads();
        if (t < cnt) { s_src[t] = csr_s[base + t]; s_w[t] = csr_w[base + t]; }
        __syncthreads();
        for (int i = 0; i < cnt; ++i) {
            const int s = s_src[i];
            const float w = s_w[i];
            const uint4 v = *reinterpret_cast<const uint4*>(Hp + (size_t)s * FDIM + fb);
            float f[8]; unp8(v, f);
#pragma unroll
            for (int j = 0; j < 8; ++j) acc[j] = fmaf(w, f[j], acc[j]);
        }
    }
    const float di = dinv[n];
    const float sw = 2.f * di * di;
    {
        const uint4 v = *reinterpret_cast<const uint4*>(Hp + (size_t)n * FDIM + fb);
        float f[8]; unp8(v, f);
#pragma unroll
        for (int j = 0; j < 8; ++j) acc[j] = fmaf(sw, f[j], acc[j]);
    }
    float bb[8];
    *(float4*)(bb)     = *(const float4*)(bias + fb);
    *(float4*)(bb + 4) = *(const float4*)(bias + fb + 4);
    float r[8];
#pragma unroll
    for (int j = 0; j < 8; ++j) r[j] = fmaxf(acc[j] + bb[j], 0.f);
    *reinterpret_cast<uint4*>(outb + (size_t)n * FDIM + fb) = pk8(r);
}

// ---------------- LSTM pointwise (H=C=0 simplification) ----------------
// Cn = sigmoid(gi)*tanh(gc); Hn = sigmoid(go + wc2[f]*Cn)*tanh(Cn)
// Ho may alias gi (in-place): thread-local index-aligned read-then-write.
__global__ void k_lstm_act(const u16* gi, const u16* __restrict__ gc,
                           const u16* __restrict__ go, const float* __restrict__ wc2,
                           u16* Ho) {
    const int i = blockIdx.x * 256 + threadIdx.x;
    const size_t base = (size_t)i * 8;
    const int f = (int)(base & (FDIM - 1));
    const uint4 vi = *(const uint4*)(gi + base);
    const uint4 vc = *(const uint4*)(gc + base);
    const uint4 vo = *(const uint4*)(go + base);
    float fi[8], fc[8], fo[8], w[8], h[8];
    unp8(vi, fi); unp8(vc, fc); unp8(vo, fo);
    *(float4*)(w)     = *(const float4*)(wc2 + f);
    *(float4*)(w + 4) = *(const float4*)(wc2 + f + 4);
#pragma unroll
    for (int j = 0; j < 8; ++j) {
        const float I  = 1.f / (1.f + __expf(-fi[j]));
        const float Cn = I * tanhf(fc[j]);
        const float O  = 1.f / (1.f + __expf(-(fo[j] + w[j] * Cn)));
        h[j] = O * tanhf(Cn);
    }
    *(uint4*)(Ho + base) = pk8(h);
}

// ---------------- final: relu -> [2048,9] linear -> log_softmax over triples ----------------
__global__ __launch_bounds__(256) void k_final(const u16* __restrict__ Hf,
                                               const float* __restrict__ lw,
                                               const float* __restrict__ lb,
                                               float* __restrict__ out) {
    const int n = blockIdx.x, t = threadIdx.x;
    float p[9] = {0.f, 0.f, 0.f, 0.f, 0.f, 0.f, 0.f, 0.f, 0.f};
    for (int f = t; f < FDIM; f += 256) {
        float h = __uint_as_float(((u32)Hf[(size_t)n * FDIM + f]) << 16);
        h = fmaxf(h, 0.f);
#pragma unroll
        for (int j = 0; j < 9; ++j) p[j] = fmaf(h, lw[j * FDIM + f], p[j]);
    }
    __shared__ float red[9][256];
#pragma unroll
    for (int j = 0; j < 9; ++j) red[j][t] = p[j];
    __syncthreads();
    for (int s = 128; s > 0; s >>= 1) {
        if (t < s) {
#pragma unroll
            for (int j = 0; j < 9; ++j) red[j][t] += red[j][t + s];
        }
        __syncthreads();
    }
    if (t == 0) {
        float y[9];
#pragma unroll
        for (int j = 0; j < 9; ++j) y[j] = red[j][0] + lb[j];
#pragma unroll
        for (int g = 0; g < 3; ++g) {
            const float a = y[g * 3], b = y[g * 3 + 1], c = y[g * 3 + 2];
            const float m = fmaxf(a, fmaxf(b, c));
            const float lse = m + logf(__expf(a - m) + __expf(b - m) + __expf(c - m));
            out[n * 9 + g * 3 + 0] = a - lse;
            out[n * 9 + g * 3 + 1] = b - lse;
            out[n * 9 + g * 3 + 2] = c - lse;
        }
    }
}

// ---------------- launcher ----------------
extern "C" void kernel_launch(void* const* d_in, const int* in_sizes, int n_in,
                              void* d_out, int out_size, void* d_ws, size_t ws_size,
                              hipStream_t stream) {
    const float* x   = (const float*)d_in[0];
    const int*   ei  = (const int*)d_in[1];
    const float* g1w = (const float*)d_in[3];
    const float* g1b = (const float*)d_in[4];
    const float* g2w = (const float*)d_in[5];
    const float* g2b = (const float*)d_in[6];
    const float* Wx  = (const float*)d_in[7];
    // d_in[8] = lstm_Th: dead (H=0)
    const float* bch = (const float*)d_in[9];
    const float* wcv = (const float*)d_in[10];
    const float* bb  = (const float*)d_in[11];
    const float* lw  = (const float*)d_in[12];
    const float* lb  = (const float*)d_in[13];
    float* out = (float*)d_out;

    const int NE = in_sizes[1] / 2;  // 131072
    const size_t FF = (size_t)FDIM * FDIM;
    const int gsel[3] = {0, 2, 3};   // gates i, c, o

    // --- workspace layout (ws = 768 MiB measured; need ~161 MB) ---
    const size_t BUF = (FF * 2 + 255) & ~(size_t)255;
    const size_t csr_bytes = ((size_t)FDIM * 8 + ((size_t)FDIM + 1) * 4 + (size_t)FDIM * 4
                              + (size_t)NE * 8 + 4 * 256);
    const size_t needed = 4 * BUF + 11 * BUF + 2 * FF * 4 + csr_bytes + 1024;

    char* wp = (char*)d_ws;
    bool fallback = (ws_size < needed);  // aliased layout: garbage output, no OOB fault
    auto alloc = [&](size_t bytes) -> void* {
        if (fallback) return d_ws;
        void* p = (void*)wp;
        wp += (bytes + 255) & ~(size_t)255;
        return p;
    };
    u16* A0  = (u16*)alloc(FF * 2);
    u16* A1  = (u16*)alloc(FF * 2);
    u16* G1  = (u16*)alloc(FF * 2);
    u16* G2  = (u16*)alloc(FF * 2);
    u16* WT  = (u16*)alloc(11 * FF * 2);     // 11 transposed bf16 weights, contiguous
    float* Pf = (float*)alloc(2 * FF * 4);   // split-K fp32 partials
    int*   counts;
    int*   off;
    float* dinv;
    int*   csr_s;
    float* csr_w;
    if (!fallback) {
        counts = (int*)alloc((size_t)FDIM * 4 * 2);
        off    = (int*)alloc(((size_t)FDIM + 1) * 4);
        dinv   = (float*)alloc((size_t)FDIM * 4);
        csr_s  = (int*)alloc((size_t)NE * 4);
        csr_w  = (float*)alloc((size_t)NE * 4);
    } else {
        char* base = (char*)d_ws;
        counts = (int*)base;
        off    = (int*)(base + (size_t)64 * 1024);
        dinv   = (float*)(base + (size_t)128 * 1024);
        csr_s  = (int*)(base + (size_t)1024 * 1024);
        csr_w  = (float*)(base + (size_t)2048 * 1024);
    }
    int* cursor = counts + FDIM;

    const int eb = (NE + 255) / 256;
    const dim3 gb(256);

    // all 11 weight transposes in ONE launch (pure-input, no pipeline dependency)
    TranspArgs ta;
    ta.W[0] = g1w;
    ta.W[1] = g2w;
    for (int l = 0; l < 3; ++l)
        for (int s = 0; s < 3; ++s)
            ta.W[2 + l * 3 + s] = Wx + (size_t)(l * 4 + gsel[s]) * FF;
    ta.WT = WT;
    k_transp_all<<<dim3(64, 64, 11), dim3(1024), 0, stream>>>(ta);

    // CSR build
    k_zero<<<dim3((2 * FDIM + 255) / 256), dim3(256), 0, stream>>>(counts, 2 * FDIM);
    k_hist<<<dim3(eb), dim3(256), 0, stream>>>(ei, counts, NE);
    k_scan<<<dim3(1), dim3(1024), 0, stream>>>(counts, off, dinv);
    k_fill<<<dim3(eb), dim3(256), 0, stream>>>(ei, off, cursor, dinv, csr_s, csr_w, NE);

    // x -> bf16
    k_f2b8<<<dim3(2048), dim3(256), 0, stream>>>(x, A0);

    // GCN layer 1: h_pre = A0 @ W1 (split-K) -> A1 ; gather(A1) -> G1
    k_gemm_sk<<<dim3(16, 16, 2), gb, 0, stream>>>(A0, WT, Pf);
    k_comb<<<dim3(2048), dim3(256), 0, stream>>>(Pf, A1);
    k_gather<<<dim3(FDIM), dim3(256), 0, stream>>>(A1, off, csr_s, csr_w, dinv, g1b, G1);
    // GCN layer 2: h_pre = G1 @ W2 (split-K) -> A1 ; gather(A1) -> A0
    k_gemm_sk<<<dim3(16, 16, 2), gb, 0, stream>>>(G1, WT + FF, Pf);
    k_comb<<<dim3(2048), dim3(256), 0, stream>>>(Pf, A1);
    k_gather<<<dim3(FDIM), dim3(256), 0, stream>>>(A1, off, csr_s, csr_w, dinv, g2b, A0);

    // 3 GCLSTM layers (gates i, c, o; f-gate and Th dead since H=C=0).
    // Gate-i buffer doubles as H output (in-place act) -> A0/A1 ping-pong.
    u16* cur = A0;
    u16* alt = A1;
    for (int l = 0; l < 3; ++l) {
        u16* gouts[3] = {alt, G1, G2};  // gi -> alt (becomes next cur), gc -> G1, go -> G2
        GemmArgs gl;
        gl.A = cur;
        for (int s = 0; s < 3; ++s) {
            gl.Bt[s] = WT + (size_t)(2 + l * 3 + s) * FF;
            gl.C[s]  = gouts[s];
            gl.b1[s] = bch + (size_t)(l * 4 + gsel[s]) * FDIM;
            gl.b2[s] = bb  + (size_t)(l * 4 + gsel[s]) * FDIM;
        }
        k_gemm<<<dim3(16, 16, 3), gb, 0, stream>>>(gl);
        k_lstm_act<<<dim3(2048), dim3(256), 0, stream>>>(alt, G1, G2,
                                                         wcv + (size_t)(l * 3 + 2) * FDIM, alt);
        u16* tmp = cur; cur = alt; alt = tmp;  // H now in old `alt`
    }

    // final head (cur holds H of last LSTM layer)
    k_final<<<dim3(FDIM), dim3(256), 0, stream>>>(cur, lw, lb, out);
}